// Round 3
// baseline (752.874 us; speedup 1.0000x reference)
//
#include <hip/hip_runtime.h>

typedef unsigned short u16;
typedef unsigned int u32;
typedef __attribute__((ext_vector_type(8))) __bf16 bf16x8;
typedef __attribute__((ext_vector_type(4))) float f32x4;

constexpr int Bn = 1024, Dn = 2048, Pn = 16384, Cn = 8192, Kp = 8;
constexpr float INV_TEMP = 20.0f;
constexpr int KNN = 50;
constexpr float NEGV = -1e4f;

__device__ __forceinline__ u16 f32_to_bf16_bits(float f) {
  const u32 u = __float_as_uint(f);
  return (u16)((u + 0x7FFFu + ((u >> 16) & 1u)) >> 16);  // RNE; exact if f is bf16-rounded
}

// ---------- block reductions (256 threads, 4 waves) ----------
__device__ __forceinline__ float blk_max(float v, float* red) {
#pragma unroll
  for (int off = 32; off > 0; off >>= 1) v = fmaxf(v, __shfl_xor(v, off));
  if ((threadIdx.x & 63) == 0) red[threadIdx.x >> 6] = v;
  __syncthreads();
  float r = fmaxf(fmaxf(red[0], red[1]), fmaxf(red[2], red[3]));
  __syncthreads();
  return r;
}
__device__ __forceinline__ float blk_sum(float v, float* red) {
#pragma unroll
  for (int off = 32; off > 0; off >>= 1) v += __shfl_xor(v, off);
  if ((threadIdx.x & 63) == 0) red[threadIdx.x >> 6] = v;
  __syncthreads();
  float r = red[0] + red[1] + red[2] + red[3];
  __syncthreads();
  return r;
}
__device__ __forceinline__ int blk_sum_i(int v, int* red) {
#pragma unroll
  for (int off = 32; off > 0; off >>= 1) v += __shfl_xor(v, off);
  if ((threadIdx.x & 63) == 0) red[threadIdx.x >> 6] = v;
  __syncthreads();
  int r = red[0] + red[1] + red[2] + red[3];
  __syncthreads();
  return r;
}

// ---------- dtype sniff: is the float data bf16 (flag=1) or fp32 (flag=0)? --
// Row 0 of `inputs` is L2-normalized: sum of squares == 1 under the TRUE
// interpretation; the wrong interpretation gives ~2.3 (bf16 data read as
// fp32) or astronomically large/inf (fp32 mantissa halves read as bf16).
__global__ __launch_bounds__(256) void sniff(const void* __restrict__ A,
                                             int* __restrict__ flag) {
  __shared__ float redf[4];
  const int tid = threadIdx.x;
  const float* af = (const float*)A;
  const u16* ab = (const u16*)A;
  float s2 = 0.f, s2b = 0.f;
  for (int i = tid; i < Dn; i += 256) {
    const float x = af[i];
    s2 += x * x;
    const float y = __uint_as_float(((u32)ab[i]) << 16);
    s2b += y * y;
  }
  s2 = blk_sum(s2, redf);
  s2b = blk_sum(s2b, redf);
  if (tid == 0) {
    // NaN/inf in s2b compares false -> picks fp32, as desired
    flag[0] = (fabsf(s2b - 1.f) < fabsf(s2 - 1.f)) ? 1 : 0;
  }
}

// ---------- GEMM: C[1024,N] = scale * A[1024,K] . B[N,K]^T ----------
// Manual LDS staging with in-register fp32->bf16 convert (or raw bf16 copy),
// then 16x16x32 bf16 MFMA, 128x128 tile, BK=32, 4 waves in 2x2.
__global__ __launch_bounds__(256) void gemm_bt(
    const void* __restrict__ Av, const void* __restrict__ Bv,
    const int* __restrict__ flag, float* __restrict__ C,
    int N, int K, float scale)
{
  __shared__ __align__(16) u16 As[128 * 32];
  __shared__ __align__(16) u16 Bs[128 * 32];
  const int tid  = threadIdx.x;
  const int lane = tid & 63;
  const int wave = tid >> 6;
  const int tileM = blockIdx.y * 128;
  const int tileN = blockIdx.x * 128;
  const int wm = (wave & 1) * 64;
  const int wn = (wave >> 1) * 64;
  const int quad = lane >> 4;
  const int r16  = lane & 15;
  const bool isBf16 = (*flag != 0);

  f32x4 acc[4][4] = {};

  for (int k0 = 0; k0 < K; k0 += 32) {
    // stage 128x32 tiles: 1024 4-element units, 4 per thread
#pragma unroll
    for (int r = 0; r < 4; ++r) {
      const int idx = tid + 256 * r;     // 0..1023
      const int row = idx >> 3;          // 0..127
      const int c   = (idx & 7) * 4;     // 0,4,...,28
      u16* da = &As[row * 32 + c];
      u16* db = &Bs[row * 32 + c];
      if (isBf16) {
        const u16* a16 = (const u16*)Av;
        const u16* b16 = (const u16*)Bv;
        *(ushort4*)da = *(const ushort4*)(a16 + (size_t)(tileM + row) * K + k0 + c);
        *(ushort4*)db = *(const ushort4*)(b16 + (size_t)(tileN + row) * K + k0 + c);
      } else {
        const float* a32 = (const float*)Av;
        const float* b32 = (const float*)Bv;
        const float4 va = *(const float4*)(a32 + (size_t)(tileM + row) * K + k0 + c);
        const float4 vb = *(const float4*)(b32 + (size_t)(tileN + row) * K + k0 + c);
        ushort4 pa, pb;
        pa.x = f32_to_bf16_bits(va.x); pa.y = f32_to_bf16_bits(va.y);
        pa.z = f32_to_bf16_bits(va.z); pa.w = f32_to_bf16_bits(va.w);
        pb.x = f32_to_bf16_bits(vb.x); pb.y = f32_to_bf16_bits(vb.y);
        pb.z = f32_to_bf16_bits(vb.z); pb.w = f32_to_bf16_bits(vb.w);
        *(ushort4*)da = pa;
        *(ushort4*)db = pb;
      }
    }
    __syncthreads();
    bf16x8 af[4], bfr[4];
#pragma unroll
    for (int i = 0; i < 4; ++i)
      af[i] = *(const bf16x8*)&As[(wm + i * 16 + r16) * 32 + quad * 8];
#pragma unroll
    for (int j = 0; j < 4; ++j)
      bfr[j] = *(const bf16x8*)&Bs[(wn + j * 16 + r16) * 32 + quad * 8];
#pragma unroll
    for (int i = 0; i < 4; ++i)
#pragma unroll
      for (int j = 0; j < 4; ++j)
        acc[i][j] = __builtin_amdgcn_mfma_f32_16x16x32_bf16(af[i], bfr[j], acc[i][j], 0, 0, 0);
    __syncthreads();
  }

  // C/D layout (verified m89/m91): col = lane&15, row = quad*4 + reg
#pragma unroll
  for (int i = 0; i < 4; ++i)
#pragma unroll
    for (int j = 0; j < 4; ++j) {
      const int ccol = tileN + wn + j * 16 + r16;
#pragma unroll
      for (int rg = 0; rg < 4; ++rg) {
        const int rrow = tileM + wm + i * 16 + quad * 4 + rg;
        C[(size_t)rrow * N + ccol] = scale * acc[i][j][rg];
      }
    }
}

// ---------- per-row class CE: lse(row) - row[class] ----------
__global__ __launch_bounds__(256) void class_row(
    const float* __restrict__ scores, const int* __restrict__ classes,
    float* __restrict__ rlc)
{
  __shared__ float redf[4];
  const int b = blockIdx.x;
  const int tid = threadIdx.x;
  const float* row = scores + (size_t)b * Cn;
  float v[Cn / 256];
#pragma unroll
  for (int s = 0; s < Cn / 256; ++s) v[s] = row[s * 256 + tid];
  float m = -3.0e38f;
#pragma unroll
  for (int s = 0; s < Cn / 256; ++s) m = fmaxf(m, v[s]);
  m = blk_max(m, redf);
  float sum = 0.f;
#pragma unroll
  for (int s = 0; s < Cn / 256; ++s) sum += expf(v[s] - m);
  sum = blk_sum(sum, redf);
  if (tid == 0) {
    const int cls = classes[b];
    rlc[b] = m + logf(sum) - row[cls];
  }
}

// ---------- per-row proxy loss: exact top-50 via key binary search ----------
__global__ __launch_bounds__(256) void proxy_row(
    const float* __restrict__ scores, const int* __restrict__ l2p,
    const int* __restrict__ labels, float* __restrict__ rlp)
{
  __shared__ float redf[4];
  __shared__ int redi[4];
  __shared__ int posIdx[Kp];
  __shared__ float posVal[Kp];
  const int b = blockIdx.x;
  const int tid = threadIdx.x;
  const float* row = scores + (size_t)b * Pn;

  if (tid < Kp) {
    const int lbl = labels[b];
    const int p = l2p[lbl * Kp + tid];
    posIdx[tid] = p;
    posVal[tid] = (p >= 0) ? row[p] : NEGV;   // gather BEFORE masking
  }
  __syncthreads();

  unsigned long long excl = 0ull;
#pragma unroll
  for (int k = 0; k < Kp; ++k) {
    const int p = posIdx[k];
    if (p >= 0 && (p & 255) == tid) excl |= (1ull << (p >> 8));
  }

  u32 key[Pn / 256];
  float vmax = -3.0e38f;
#pragma unroll
  for (int s = 0; s < Pn / 256; ++s) {
    const float v = row[s * 256 + tid];
    const u32 bits = __float_as_uint(v);
    const u32 k = (bits & 0x80000000u) ? ~bits : (bits ^ 0x80000000u);
    const bool ex = (excl >> s) & 1ull;
    key[s] = ex ? 0u : k;                      // key 0 = never selected
    if (!ex) vmax = fmaxf(vmax, v);
  }
  float M = blk_max(vmax, redf);
#pragma unroll
  for (int k = 0; k < Kp; ++k) M = fmaxf(M, posVal[k]);

  // largest T with count(key >= T) >= 50  ->  T = 50th largest key
  u32 lo = 0;
  for (int bit = 31; bit >= 0; --bit) {
    const u32 cand = lo | (1u << bit);
    int c = 0;
#pragma unroll
    for (int s = 0; s < Pn / 256; ++s) c += (key[s] >= cand) ? 1 : 0;
    c = blk_sum_i(c, redi);
    if (c >= KNN) lo = cand;
  }

  int cgt = 0; float s1 = 0.f;
#pragma unroll
  for (int s = 0; s < Pn / 256; ++s) {
    if (key[s] > lo) {
      ++cgt;
      const u32 kk = key[s];
      const u32 bits = (kk & 0x80000000u) ? (kk ^ 0x80000000u) : ~kk;
      s1 += expf(__uint_as_float(bits) - M);
    }
  }
  cgt = blk_sum_i(cgt, redi);
  s1 = blk_sum(s1, redf);

  if (tid == 0) {
    const u32 tb = (lo & 0x80000000u) ? (lo ^ 0x80000000u) : ~lo;
    const float tv = __uint_as_float(tb);
    const float Sneg = s1 + (float)(KNN - cgt) * expf(tv - M);
    float Spos = 0.f, sp = 0.f; int nv = 0;
#pragma unroll
    for (int k = 0; k < Kp; ++k) {
      Spos += expf(posVal[k] - M);
      if (posIdx[k] >= 0) { sp += posVal[k]; ++nv; }
    }
    float loss = 0.f;
    if (nv > 0) loss = M + logf(Spos + Sneg) - sp / (float)nv;
    rlp[b] = loss;
  }
}

// ---------- final: mean over batch, plain fp32 store ----------
__global__ __launch_bounds__(256) void final_reduce(
    const float* __restrict__ rlp, const float* __restrict__ rlc,
    float* __restrict__ out)
{
  __shared__ float redf[4];
  const int tid = threadIdx.x;
  float acc = 0.f;
  for (int i = tid; i < Bn; i += 256) acc += rlp[i] + rlc[i];
  acc = blk_sum(acc, redf);
  if (tid == 0) out[0] = acc * (1.0f / (float)Bn);
}

extern "C" void kernel_launch(void* const* d_in, const int* in_sizes, int n_in,
                              void* d_out, int out_size, void* d_ws, size_t ws_size,
                              hipStream_t stream) {
  const void* inputs  = d_in[0];              // [B,D]  float (fp32 or bf16 - sniffed)
  const void* pcent   = d_in[1];              // [P,D]
  const void* ccent   = d_in[2];              // [C,D]
  const int* l2p      = (const int*)d_in[3];  // [C,K]
  // d_in[4] = proxies (unused by reference)
  const int* labels   = (const int*)d_in[5];  // [B]
  const int* classes  = (const int*)d_in[6];  // [B]

  char* ws = (char*)d_ws;
  float* scores = (float*)ws;                                  // 64 MB max
  float* rlc = (float*)(ws + (size_t)64 * 1024 * 1024);        // [B]
  float* rlp = rlc + Bn;                                       // [B]
  int* flag  = (int*)(rlp + Bn);                               // [1]

  sniff<<<1, 256, 0, stream>>>(inputs, flag);

  // class branch: scores[B,C], then per-row CE
  gemm_bt<<<dim3(Cn / 128, Bn / 128), 256, 0, stream>>>(
      inputs, ccent, flag, scores, Cn, Dn, INV_TEMP);
  class_row<<<Bn, 256, 0, stream>>>(scores, classes, rlc);

  // proxy branch: scores[B,P] (reuses buffer), then per-row top-50 loss
  gemm_bt<<<dim3(Pn / 128, Bn / 128), 256, 0, stream>>>(
      inputs, pcent, flag, scores, Pn, Dn, INV_TEMP);
  proxy_row<<<Bn, 256, 0, stream>>>(scores, l2p, labels, rlp);

  final_reduce<<<1, 256, 0, stream>>>(rlp, rlc, (float*)d_out);
}

// Round 4
// 510.508 us; speedup vs baseline: 1.4748x; 1.4748x over previous
//
#include <hip/hip_runtime.h>

typedef unsigned short u16;
typedef unsigned int u32;
typedef unsigned long long u64;
typedef __attribute__((ext_vector_type(8))) __bf16 bf16x8;
typedef __attribute__((ext_vector_type(4))) float f32x4;

constexpr int Bn = 1024, Dn = 2048, Pn = 16384, Cn = 8192, Kp = 8;
constexpr float INV_TEMP = 20.0f;
constexpr int KNN = 50;
constexpr float NEGV = -1e4f;

__device__ __forceinline__ u16 f32_to_bf16_bits(float f) {
  const u32 u = __float_as_uint(f);
  return (u16)((u + 0x7FFFu + ((u >> 16) & 1u)) >> 16);  // RNE; exact if f already bf16-rounded
}

// ---------- async global->LDS, 16B per lane (wave-uniform LDS base) ----------
__device__ __forceinline__ void async_copy16(const void* g, void* l) {
  __builtin_amdgcn_global_load_lds(
      (__attribute__((address_space(1))) void*)(g),
      (__attribute__((address_space(3))) void*)(l), 16, 0, 0);
}

// ---------- block reductions (256 threads, 4 waves) ----------
__device__ __forceinline__ float blk_max(float v, float* red) {
#pragma unroll
  for (int off = 32; off > 0; off >>= 1) v = fmaxf(v, __shfl_xor(v, off));
  if ((threadIdx.x & 63) == 0) red[threadIdx.x >> 6] = v;
  __syncthreads();
  float r = fmaxf(fmaxf(red[0], red[1]), fmaxf(red[2], red[3]));
  __syncthreads();
  return r;
}
__device__ __forceinline__ float blk_sum(float v, float* red) {
#pragma unroll
  for (int off = 32; off > 0; off >>= 1) v += __shfl_xor(v, off);
  if ((threadIdx.x & 63) == 0) red[threadIdx.x >> 6] = v;
  __syncthreads();
  float r = red[0] + red[1] + red[2] + red[3];
  __syncthreads();
  return r;
}
__device__ __forceinline__ int blk_sum_i(int v, int* red) {
#pragma unroll
  for (int off = 32; off > 0; off >>= 1) v += __shfl_xor(v, off);
  if ((threadIdx.x & 63) == 0) red[threadIdx.x >> 6] = v;
  __syncthreads();
  int r = red[0] + red[1] + red[2] + red[3];
  __syncthreads();
  return r;
}

// ---------- dtype sniff: fp32 (flag=0) or bf16 (flag=1)? ----------
__global__ __launch_bounds__(256) void sniff(const void* __restrict__ A,
                                             int* __restrict__ flag) {
  __shared__ float redf[4];
  const int tid = threadIdx.x;
  const float* af = (const float*)A;
  const u16* ab = (const u16*)A;
  float s2 = 0.f, s2b = 0.f;
  for (int i = tid; i < Dn; i += 256) {
    const float x = af[i];
    s2 += x * x;
    const float y = __uint_as_float(((u32)ab[i]) << 16);
    s2b += y * y;
  }
  s2 = blk_sum(s2, redf);
  s2b = blk_sum(s2b, redf);
  if (tid == 0) flag[0] = (fabsf(s2b - 1.f) < fabsf(s2 - 1.f)) ? 1 : 0;
}

// ---------- fp32 (or bf16) -> packed bf16, 8 elements per thread-iter -------
__global__ __launch_bounds__(256) void to_bf16(
    const void* __restrict__ src, u16* __restrict__ dst, int n8,
    const int* __restrict__ flag) {
  const bool isBf16 = (*flag != 0);
  int i = blockIdx.x * 256 + threadIdx.x;
  const int stride = gridDim.x * 256;
  for (; i < n8; i += stride) {
    if (isBf16) {
      ((ulonglong2*)dst)[i] = ((const ulonglong2*)src)[i];
    } else {
      const float4 a = ((const float4*)src)[2 * i];
      const float4 b = ((const float4*)src)[2 * i + 1];
      ushort4 p, q;
      p.x = f32_to_bf16_bits(a.x); p.y = f32_to_bf16_bits(a.y);
      p.z = f32_to_bf16_bits(a.z); p.w = f32_to_bf16_bits(a.w);
      q.x = f32_to_bf16_bits(b.x); q.y = f32_to_bf16_bits(b.y);
      q.z = f32_to_bf16_bits(b.z); q.w = f32_to_bf16_bits(b.w);
      ((ushort4*)dst)[2 * i] = p;
      ((ushort4*)dst)[2 * i + 1] = q;
    }
  }
}

// ---------- m97 GEMM: C[M,N] = scale * A[M,K] . B[N,K]^T, bf16 in / f32 out -
// 128x128 tile, BK=32, global_load_lds width=16, 4 waves 2x2, 4x4 MFMA/wave.
__global__ __launch_bounds__(256) void gemm_bt_bf16(
    const u16* __restrict__ A, const u16* __restrict__ Bm,
    float* __restrict__ C, int N, int K, float scale)
{
  __shared__ __align__(16) u16 As[128 * 32];
  __shared__ __align__(16) u16 Bs[128 * 32];
  const int tid  = threadIdx.x;
  const int lane = tid & 63;
  const int wave = tid >> 6;
  const int tileM = blockIdx.y * 128;
  const int tileN = blockIdx.x * 128;
  const int wm = (wave & 1) * 64;
  const int wn = (wave >> 1) * 64;
  const int quad = lane >> 4;
  const int r16  = lane & 15;

  f32x4 acc[4][4] = {};

  const int rowInChunk = lane >> 2;        // 4 lanes per 64B row
  const int colOff = (lane & 3) * 8;       // 8 bf16 = 16B per lane

  for (int k0 = 0; k0 < K; k0 += 32) {
#pragma unroll
    for (int j = 0; j < 2; ++j) {
      const int chunk = wave * 2 + j;              // 0..7, wave-uniform
      const int row = chunk * 16 + rowInChunk;     // 0..127
      const u16* ga = A  + (size_t)(tileM + row) * K + (k0 + colOff);
      const u16* gb = Bm + (size_t)(tileN + row) * K + (k0 + colOff);
      async_copy16(ga, &As[chunk * 512]);          // lane-scatter: base + lane*16B
      async_copy16(gb, &Bs[chunk * 512]);
    }
    __syncthreads();   // compiler emits s_waitcnt vmcnt(0) before s_barrier
    bf16x8 af[4], bfr[4];
#pragma unroll
    for (int i = 0; i < 4; ++i)
      af[i] = *(const bf16x8*)&As[(wm + i * 16 + r16) * 32 + quad * 8];
#pragma unroll
    for (int j = 0; j < 4; ++j)
      bfr[j] = *(const bf16x8*)&Bs[(wn + j * 16 + r16) * 32 + quad * 8];
#pragma unroll
    for (int i = 0; i < 4; ++i)
#pragma unroll
      for (int j = 0; j < 4; ++j)
        acc[i][j] = __builtin_amdgcn_mfma_f32_16x16x32_bf16(af[i], bfr[j], acc[i][j], 0, 0, 0);
    __syncthreads();
  }

  // C/D layout (verified m89/m91): col = lane&15, row = quad*4 + reg
#pragma unroll
  for (int i = 0; i < 4; ++i)
#pragma unroll
    for (int j = 0; j < 4; ++j) {
      const int ccol = tileN + wn + j * 16 + r16;
#pragma unroll
      for (int rg = 0; rg < 4; ++rg) {
        const int rrow = tileM + wm + i * 16 + quad * 4 + rg;
        C[(size_t)rrow * N + ccol] = scale * acc[i][j][rg];
      }
    }
}

// ---------- fallback GEMM (round-3): manual staging, runtime dtype ----------
__global__ __launch_bounds__(256) void gemm_bt_f32(
    const void* __restrict__ Av, const void* __restrict__ Bv,
    const int* __restrict__ flag, float* __restrict__ C,
    int N, int K, float scale)
{
  __shared__ __align__(16) u16 As[128 * 32];
  __shared__ __align__(16) u16 Bs[128 * 32];
  const int tid  = threadIdx.x;
  const int lane = tid & 63;
  const int wave = tid >> 6;
  const int tileM = blockIdx.y * 128;
  const int tileN = blockIdx.x * 128;
  const int wm = (wave & 1) * 64;
  const int wn = (wave >> 1) * 64;
  const int quad = lane >> 4;
  const int r16  = lane & 15;
  const bool isBf16 = (*flag != 0);

  f32x4 acc[4][4] = {};

  for (int k0 = 0; k0 < K; k0 += 32) {
#pragma unroll
    for (int r = 0; r < 4; ++r) {
      const int idx = tid + 256 * r;
      const int row = idx >> 3;
      const int c   = (idx & 7) * 4;
      u16* da = &As[row * 32 + c];
      u16* db = &Bs[row * 32 + c];
      if (isBf16) {
        const u16* a16 = (const u16*)Av;
        const u16* b16 = (const u16*)Bv;
        *(ushort4*)da = *(const ushort4*)(a16 + (size_t)(tileM + row) * K + k0 + c);
        *(ushort4*)db = *(const ushort4*)(b16 + (size_t)(tileN + row) * K + k0 + c);
      } else {
        const float* a32 = (const float*)Av;
        const float* b32 = (const float*)Bv;
        const float4 va = *(const float4*)(a32 + (size_t)(tileM + row) * K + k0 + c);
        const float4 vb = *(const float4*)(b32 + (size_t)(tileN + row) * K + k0 + c);
        ushort4 pa, pb;
        pa.x = f32_to_bf16_bits(va.x); pa.y = f32_to_bf16_bits(va.y);
        pa.z = f32_to_bf16_bits(va.z); pa.w = f32_to_bf16_bits(va.w);
        pb.x = f32_to_bf16_bits(vb.x); pb.y = f32_to_bf16_bits(vb.y);
        pb.z = f32_to_bf16_bits(vb.z); pb.w = f32_to_bf16_bits(vb.w);
        *(ushort4*)da = pa;
        *(ushort4*)db = pb;
      }
    }
    __syncthreads();
    bf16x8 af[4], bfr[4];
#pragma unroll
    for (int i = 0; i < 4; ++i)
      af[i] = *(const bf16x8*)&As[(wm + i * 16 + r16) * 32 + quad * 8];
#pragma unroll
    for (int j = 0; j < 4; ++j)
      bfr[j] = *(const bf16x8*)&Bs[(wn + j * 16 + r16) * 32 + quad * 8];
#pragma unroll
    for (int i = 0; i < 4; ++i)
#pragma unroll
      for (int j = 0; j < 4; ++j)
        acc[i][j] = __builtin_amdgcn_mfma_f32_16x16x32_bf16(af[i], bfr[j], acc[i][j], 0, 0, 0);
    __syncthreads();
  }

#pragma unroll
  for (int i = 0; i < 4; ++i)
#pragma unroll
    for (int j = 0; j < 4; ++j) {
      const int ccol = tileN + wn + j * 16 + r16;
#pragma unroll
      for (int rg = 0; rg < 4; ++rg) {
        const int rrow = tileM + wm + i * 16 + quad * 4 + rg;
        C[(size_t)rrow * N + ccol] = scale * acc[i][j][rg];
      }
    }
}

// ---------- per-row class CE: lse(row) - row[class], float4 loads ----------
__global__ __launch_bounds__(256) void class_row(
    const float* __restrict__ scores, const int* __restrict__ classes,
    float* __restrict__ rlc)
{
  __shared__ float redf[4];
  const int b = blockIdx.x;
  const int tid = threadIdx.x;
  const float* row = scores + (size_t)b * Cn;
  float4 v[Cn / 1024];
#pragma unroll
  for (int s = 0; s < Cn / 1024; ++s)
    v[s] = *(const float4*)(row + s * 1024 + tid * 4);
  float m = -3.0e38f;
#pragma unroll
  for (int s = 0; s < Cn / 1024; ++s)
    m = fmaxf(m, fmaxf(fmaxf(v[s].x, v[s].y), fmaxf(v[s].z, v[s].w)));
  m = blk_max(m, redf);
  float sum = 0.f;
#pragma unroll
  for (int s = 0; s < Cn / 1024; ++s)
    sum += expf(v[s].x - m) + expf(v[s].y - m) + expf(v[s].z - m) + expf(v[s].w - m);
  sum = blk_sum(sum, redf);
  if (tid == 0) {
    const int cls = classes[b];
    rlc[b] = m + logf(sum) - row[cls];
  }
}

// ---------- per-row proxy loss: exact top-50 via key binary search ----------
// float4 loads; element p lives at s=p>>10, tid=(p>>2)&255, j=p&3.
__global__ __launch_bounds__(256) void proxy_row(
    const float* __restrict__ scores, const int* __restrict__ l2p,
    const int* __restrict__ labels, float* __restrict__ rlp)
{
  __shared__ float redf[4];
  __shared__ int redi[4];
  __shared__ int posIdx[Kp];
  __shared__ float posVal[Kp];
  const int b = blockIdx.x;
  const int tid = threadIdx.x;
  const float* row = scores + (size_t)b * Pn;

  if (tid < Kp) {
    const int lbl = labels[b];
    const int p = l2p[lbl * Kp + tid];
    posIdx[tid] = p;
    posVal[tid] = (p >= 0) ? row[p] : NEGV;   // gather BEFORE masking
  }
  __syncthreads();

  u64 excl = 0ull;
#pragma unroll
  for (int k = 0; k < Kp; ++k) {
    const int p = posIdx[k];
    if (p >= 0 && ((p >> 2) & 255) == tid)
      excl |= (1ull << (((p >> 10) << 2) | (p & 3)));
  }

  u32 key[Pn / 256];
  float vmax = -3.0e38f;
#pragma unroll
  for (int s = 0; s < Pn / 1024; ++s) {
    const float4 v4 = *(const float4*)(row + s * 1024 + tid * 4);
    const float vv[4] = {v4.x, v4.y, v4.z, v4.w};
#pragma unroll
    for (int j = 0; j < 4; ++j) {
      const float v = vv[j];
      const u32 bits = __float_as_uint(v);
      const u32 k = (bits & 0x80000000u) ? ~bits : (bits ^ 0x80000000u);
      const bool ex = (excl >> (s * 4 + j)) & 1ull;
      key[s * 4 + j] = ex ? 0u : k;            // key 0 = never selected
      if (!ex) vmax = fmaxf(vmax, v);
    }
  }
  float M = blk_max(vmax, redf);
#pragma unroll
  for (int k = 0; k < Kp; ++k) M = fmaxf(M, posVal[k]);

  // largest T with count(key >= T) >= 50  ->  T = 50th largest key
  u32 lo = 0;
  for (int bit = 31; bit >= 0; --bit) {
    const u32 cand = lo | (1u << bit);
    int c = 0;
#pragma unroll
    for (int s = 0; s < Pn / 256; ++s) c += (key[s] >= cand) ? 1 : 0;
    c = blk_sum_i(c, redi);
    if (c >= KNN) lo = cand;
  }

  int cgt = 0; float s1 = 0.f;
#pragma unroll
  for (int s = 0; s < Pn / 256; ++s) {
    if (key[s] > lo) {
      ++cgt;
      const u32 kk = key[s];
      const u32 bits = (kk & 0x80000000u) ? (kk ^ 0x80000000u) : ~kk;
      s1 += expf(__uint_as_float(bits) - M);
    }
  }
  cgt = blk_sum_i(cgt, redi);
  s1 = blk_sum(s1, redf);

  if (tid == 0) {
    const u32 tb = (lo & 0x80000000u) ? (lo ^ 0x80000000u) : ~lo;
    const float tv = __uint_as_float(tb);
    const float Sneg = s1 + (float)(KNN - cgt) * expf(tv - M);
    float Spos = 0.f, sp = 0.f; int nv = 0;
#pragma unroll
    for (int k = 0; k < Kp; ++k) {
      Spos += expf(posVal[k] - M);
      if (posIdx[k] >= 0) { sp += posVal[k]; ++nv; }
    }
    float loss = 0.f;
    if (nv > 0) loss = M + logf(Spos + Sneg) - sp / (float)nv;
    rlp[b] = loss;
  }
}

// ---------- final: mean over batch, fp32 store ----------
__global__ __launch_bounds__(256) void final_reduce(
    const float* __restrict__ rlp, const float* __restrict__ rlc,
    float* __restrict__ out)
{
  __shared__ float redf[4];
  const int tid = threadIdx.x;
  float acc = 0.f;
  for (int i = tid; i < Bn; i += 256) acc += rlp[i] + rlc[i];
  acc = blk_sum(acc, redf);
  if (tid == 0) out[0] = acc * (1.0f / (float)Bn);
}

extern "C" void kernel_launch(void* const* d_in, const int* in_sizes, int n_in,
                              void* d_out, int out_size, void* d_ws, size_t ws_size,
                              hipStream_t stream) {
  const void* inputs  = d_in[0];              // [B,D]  float (fp32-holding-bf16 or bf16)
  const void* pcent   = d_in[1];              // [P,D]
  const void* ccent   = d_in[2];              // [C,D]
  const int* l2p      = (const int*)d_in[3];  // [C,K]
  const int* labels   = (const int*)d_in[5];  // [B]
  const int* classes  = (const int*)d_in[6];  // [B]

  char* ws = (char*)d_ws;
  float* scores = (float*)ws;                                  // 64 MB
  size_t off = (size_t)64 * 1024 * 1024;
  float* rlc = (float*)(ws + off);  off += Bn * 4;
  float* rlp = (float*)(ws + off);  off += Bn * 4;
  int* flag  = (int*)(ws + off);    off += 4096;               // pad
  u16* Abf   = (u16*)(ws + off);    off += (size_t)Bn * Dn * 2;
  u16* Cbf   = (u16*)(ws + off);    off += (size_t)Cn * Dn * 2;
  u16* Pbf   = (u16*)(ws + off);    off += (size_t)Pn * Dn * 2;
  const bool big = (ws_size >= off);          // constant per-run -> graph-safe

  sniff<<<1, 256, 0, stream>>>(inputs, flag);

  if (big) {
    to_bf16<<<1024, 256, 0, stream>>>(inputs, Abf, Bn * Dn / 8, flag);
    to_bf16<<<2048, 256, 0, stream>>>(ccent, Cbf, Cn * Dn / 8, flag);
    to_bf16<<<4096, 256, 0, stream>>>(pcent, Pbf, Pn * Dn / 8, flag);

    gemm_bt_bf16<<<dim3(Cn / 128, Bn / 128), 256, 0, stream>>>(
        Abf, Cbf, scores, Cn, Dn, INV_TEMP);
    class_row<<<Bn, 256, 0, stream>>>(scores, classes, rlc);

    gemm_bt_bf16<<<dim3(Pn / 128, Bn / 128), 256, 0, stream>>>(
        Abf, Pbf, scores, Pn, Dn, INV_TEMP);
    proxy_row<<<Bn, 256, 0, stream>>>(scores, l2p, labels, rlp);
  } else {
    gemm_bt_f32<<<dim3(Cn / 128, Bn / 128), 256, 0, stream>>>(
        inputs, ccent, flag, scores, Cn, Dn, INV_TEMP);
    class_row<<<Bn, 256, 0, stream>>>(scores, classes, rlc);

    gemm_bt_f32<<<dim3(Pn / 128, Bn / 128), 256, 0, stream>>>(
        inputs, pcent, flag, scores, Pn, Dn, INV_TEMP);
    proxy_row<<<Bn, 256, 0, stream>>>(scores, l2p, labels, rlp);
  }

  final_reduce<<<1, 256, 0, stream>>>(rlp, rlc, (float*)d_out);
}